// Round 9
// baseline (16.067 us; speedup 1.0000x reference)
//
#include <hip/hip_runtime.h>

#define N_ 8
#define C_ 64
#define L_ 512
#define D_ 64
#define TI 8          // rows per block
#define KST 68        // k2b row stride (dwords): mult of 4, ==4 mod 32 -> b128 floor
#define XST 84        // xs row stride (dwords): >=80 staged cols; ==20 mod 32 -> b128 floor
#define AST 76        // ash row stride

#define C2F 2.8853900817779268f   // 2*log2(e)

typedef _Float16 f16x8 __attribute__((ext_vector_type(8)));
typedef float    f32x4 __attribute__((ext_vector_type(4)));

__device__ __forceinline__ float rcp_f(float x) { return __builtin_amdgcn_rcpf(x); }
__device__ __forceinline__ float ex2(float x)   { return __builtin_amdgcn_exp2f(x); }

// Single fused kernel, independent blocks; band projection on the matrix pipe.
// grid 512 = (n = bx&7 -> XCD-local batch, t = bx>>3), 512 thr = 8 waves.
// Proj: 24 units (6 M-tiles x 4 N-tiles) spread over 8 waves, 3 units each.
__global__ __launch_bounds__(512, 4) void fused_kernel(
    const float* __restrict__ x, const float* __restrict__ Wx,
    const float* __restrict__ Wt, const float* __restrict__ bh,
    const float* __restrict__ Wa,
    float* __restrict__ vout, float* __restrict__ aout)
{
  __shared__ __attribute__((aligned(16))) float xs[C_ * XST];   // [c][jj], 80 cols staged
  __shared__ __attribute__((aligned(16))) float k2b[96 * KST];  // rows 0..79 k2, 80..95 q2
  __shared__ float ash[TI * AST];   // [row][jj] shifted a, zero-padded
  __shared__ float vs[C_][9];       // [c][row]

  const int tid  = threadIdx.x;
  const int lane = tid & 63;
  const int bx   = blockIdx.x;
  const int n    = bx & 7;          // consecutive blocks -> distinct n (XCD-local x)
  const int t    = bx >> 3;
  const int i0   = t << 3;
  const int jbase = i0 - 32;

  const int w   = __builtin_amdgcn_readfirstlane(tid >> 6);   // wave id, uniform
  const int l15 = lane & 15, g = lane >> 4;

  // ---- stage loads: 80 band cols = 20 quads per c, 1280 idx ----
  float4 xv0 = {0.f,0.f,0.f,0.f}, xv1 = {0.f,0.f,0.f,0.f}, xv2 = {0.f,0.f,0.f,0.f};
  int c0, c1, c2 = 0, jj0, jj1, jj2 = 0;
  {
    int idx = tid;        c0 = idx / 20; jj0 = (idx % 20) << 2;
    int j = jbase + jj0;  // j % 4 == 0: quad fully in or out
    if (j >= 0 && j < L_) xv0 = *(const float4*)(x + (n * C_ + c0) * L_ + j);
  }
  {
    int idx = tid + 512;  c1 = idx / 20; jj1 = (idx % 20) << 2;
    int j = jbase + jj1;
    if (j >= 0 && j < L_) xv1 = *(const float4*)(x + (n * C_ + c1) * L_ + j);
  }
  if (tid < 256) {
    int idx = tid + 1024; c2 = idx / 20; jj2 = (idx % 20) << 2;
    int j = jbase + jj2;
    if (j >= 0 && j < L_) xv2 = *(const float4*)(x + (n * C_ + c2) * L_ + j);
  }

  // ---- B prefetch: units u = 3w..3w+2, u = mt*4 + nt (issued pre-barrier) ----
  float bpre[3][2][8];
  #pragma unroll
  for (int u3 = 0; u3 < 3; ++u3) {
    const int u = w * 3 + u3, mt = u >> 2, nt = u & 3;
    const float* Wm = (mt < 5) ? Wx : Wt;
    #pragma unroll
    for (int kk = 0; kk < 2; ++kk)
      #pragma unroll
      for (int e = 0; e < 8; ++e)
        bpre[u3][kk][e] = Wm[(g * 8 + kk * 32 + e) * D_ + nt * 16 + l15];
  }

  // ---- stage writes (b128) ----
  *(float4*)&xs[c0 * XST + jj0] = xv0;
  *(float4*)&xs[c1 * XST + jj1] = xv1;
  if (tid < 256) *(float4*)&xs[c2 * XST + jj2] = xv2;

  // ---- convert B to f16 (pre-barrier; barrier drains loads anyway) ----
  f16x8 b16[3][2];
  #pragma unroll
  for (int u3 = 0; u3 < 3; ++u3)
    #pragma unroll
    for (int kk = 0; kk < 2; ++kk)
      #pragma unroll
      for (int e = 0; e < 8; ++e)
        b16[u3][kk][e] = (_Float16)bpre[u3][kk][e];

  __syncthreads();

  // ---- MFMA proj: A from xs (in-register cvt, C2F folded), bias in acc ----
  #pragma unroll
  for (int u3 = 0; u3 < 3; ++u3) {
    const int u = w * 3 + u3, mt = u >> 2, nt = u & 3;
    const int abase = (mt < 5) ? mt * 16 : 32;       // band col of A-row 0
    const int drow  = ((mt < 5) ? mt * 16 : 80) + g * 4;
    f16x8 af0, af1;
    #pragma unroll
    for (int e = 0; e < 8; ++e) {
      af0[e] = (_Float16)(xs[(g * 8 + e) * XST + abase + l15] * C2F);
      af1[e] = (_Float16)(xs[(g * 8 + e + 32) * XST + abase + l15] * C2F);
    }
    f32x4 acc = {0.f, 0.f, 0.f, 0.f};
    if (mt == 5) {                                    // q-tile: bias in C-init
      float b = bh[nt * 16 + l15] * C2F;
      acc[0] = b; acc[1] = b; acc[2] = b; acc[3] = b;
    }
    acc = __builtin_amdgcn_mfma_f32_16x16x32_f16(af0, b16[u3][0], acc, 0, 0, 0);
    acc = __builtin_amdgcn_mfma_f32_16x16x32_f16(af1, b16[u3][1], acc, 0, 0, 0);
    float* dp = &k2b[drow * KST + nt * 16 + l15];
    dp[0]       = acc[0];
    dp[KST]     = acc[1];
    dp[2 * KST] = acc[2];
    dp[3 * KST] = acc[3];
  }
  __syncthreads();

  // ---- score row i = i0 + w: lane = band position, b128 k-reads ----
  const int i = i0 + w;
  const float* kp = &k2b[(w + lane) * KST];
  const float* qp = &k2b[(80 + w) * KST];   // uniform -> broadcast b128
  float a0 = 0.f, a1 = 0.f, a2 = 0.f, a3 = 0.f;
  #pragma unroll 4
  for (int dc = 0; dc < D_; dc += 4) {
    float4 kv = *(const float4*)(kp + dc);
    float4 qv = *(const float4*)(qp + dc);
    float4 wv = *(const float4*)(Wa + dc);  // uniform -> s_load
    a0 = fmaf(rcp_f(ex2(kv.x + qv.x) + 1.f), wv.x, a0);   // sigma(-2x)*Wa_d
    a1 = fmaf(rcp_f(ex2(kv.y + qv.y) + 1.f), wv.y, a1);
    a2 = fmaf(rcp_f(ex2(kv.z + qv.z) + 1.f), wv.z, a2);
    a3 = fmaf(rcp_f(ex2(kv.w + qv.w) + 1.f), wv.w, a3);
  }
  const float acc = (a0 + a1) + (a2 + a3);

  // ---- band softmax (raw = const - 2*acc -> band max == acc min) ----
  const int j = i - 32 + lane;
  const bool valid = (j >= 0) && (j < L_);
  float m = valid ? acc : 1e30f;
  #pragma unroll
  for (int off = 32; off; off >>= 1) m = fminf(m, __shfl_xor(m, off, 64));
  float p = valid ? ex2(C2F * (m - acc)) : 0.f;
  float s = p;
  #pragma unroll
  for (int off = 32; off; off >>= 1) s += __shfl_xor(s, off, 64);
  const float av = p * rcp_f(s + 1e-6f);

  // shifted a row: ash[w][jj] = a[jj - w], zero elsewhere (same-wave use only)
  float* arow_s = &ash[w * AST];
  arow_s[lane] = 0.f;
  if (lane < AST - 64) arow_s[64 + lane] = 0.f;
  arow_s[w + lane] = av;

  // coalesced a-row global write: rotate so lane L holds col === L (mod 64)
  {
    const int src  = (lane - i + 32) & 63;
    const float ar = __shfl(av, src, 64);
    const int jsrc = i - 32 + src;            // === lane (mod 64)
    const int seg  = (jsrc >= 0) ? (jsrc >> 6) : 9;
    float* arow = aout + (size_t)(n * L_ + i) * L_;
    #pragma unroll
    for (int s8 = 0; s8 < 8; ++s8)
      arow[s8 * 64 + lane] = (s8 == seg) ? ar : 0.f;
  }

  // ---- v(row i) = sum_jj ash[jj] * xs[c][jj], lane = c, all-b128 ----
  {
    const int qstart = w & ~3;                // quad window [qstart, qstart+68)
    float v = 0.f;
    const float* xp = &xs[lane * XST];
    #pragma unroll 4
    for (int tq = 0; tq < 17; ++tq) {
      const int jj = qstart + 4 * tq;
      float4 a4 = *(const float4*)(arow_s + jj);   // uniform broadcast
      float4 xq = *(const float4*)(xp + jj);       // strided b128, floor banks
      v = fmaf(a4.x, xq.x, v);
      v = fmaf(a4.y, xq.y, v);
      v = fmaf(a4.z, xq.z, v);
      v = fmaf(a4.w, xq.w, v);
    }
    vs[lane][w] = v;
  }
  __syncthreads();
  {
    int c = tid >> 3, il = tid & 7;
    vout[((size_t)n * C_ + c) * L_ + i0 + il] = vs[c][il];
  }
}

extern "C" void kernel_launch(void* const* d_in, const int* in_sizes, int n_in,
                              void* d_out, int out_size, void* d_ws, size_t ws_size,
                              hipStream_t stream) {
  const float* x  = (const float*)d_in[0];
  const float* Wx = (const float*)d_in[1];   // key proj
  const float* Wt = (const float*)d_in[2];   // query proj
  const float* bh = (const float*)d_in[3];
  const float* Wa = (const float*)d_in[4];
  // d_in[5] (ba) cancels in the softmax: unused.
  (void)d_ws; (void)ws_size;

  float* vout = (float*)d_out;               // N*C*L
  float* aout = vout + N_ * C_ * L_;         // N*L*L

  fused_kernel<<<512, 512, 0, stream>>>(x, Wx, Wt, bh, Wa, vout, aout);
}